// Round 9
// baseline (277.085 us; speedup 1.0000x reference)
//
#include <hip/hip_runtime.h>
#include <cstdint>

#define NPX 2304      // 48*48
#define MM 6912       // 3*2304
#define NW 108        // MM/64
#define TOPK 2000
#define NEGV -1000000000.0f
#define OBJ_THRF 0.3f
#define IOU_THRF 0.7f
#define IMGF 768.0f
#define KSPLIT 8      // conv k-splits: 32 ic per split

typedef unsigned long long u64;
typedef unsigned int u32;

__device__ __forceinline__ u64 shfl64(u64 v, int src) {
  int lo = __shfl((int)(v & 0xffffffffull), src, 64);
  int hi = __shfl((int)(v >> 32), src, 64);
  return ((u64)(u32)hi << 32) | (u32)lo;
}

// ---------------- weight transpose ----------------
__global__ __launch_bounds__(256) void k_wt(const float* __restrict__ cw,
                                            float* __restrict__ wt) {
  __shared__ float t[64][65];
  const int it0 = blockIdx.x * 64;   // grid.x = 36 (2304/64)
  const int oc0 = blockIdx.y * 64;   // grid.y = 4
  const int tx = threadIdx.x & 63;
  const int ty = threadIdx.x >> 6;
#pragma unroll
  for (int k = 0; k < 16; ++k) {
    int oc = ty + k * 4;
    t[oc][tx] = cw[(oc0 + oc) * 2304 + it0 + tx];  // coalesced read
  }
  __syncthreads();
#pragma unroll
  for (int k = 0; k < 16; ++k) {
    int it = ty + k * 4;
    wt[(it0 + it) * 256 + oc0 + tx] = t[tx][it];   // coalesced write
  }
}

// ---------------- conv 3x3, 256->256, fp32, scalar-weight form ----------------
// grid (8 ks, 6 px-chunks, 16 oc-tiles) = 768 blocks x 192 thr.
// XCD property: same-ks blocks share blockid%8 -> same XCD; x + wt slices
// L2-resident (R7: FETCH 27.7 -> 3.5 MB).
// R8 lesson: weight s_load windows (144 floats/ic, SGPR budget ~96) serialize
// against 288 FMA-cyc/ic -> 51% VALUBusy. Fix: 2 px (adjacent cols) per
// thread -> 576 FMA-cyc per ic under the same weight window, 12 xv reads/ic
// for 2 px, coalesced float2 stores.
// NOTE: per-(px,oc) accumulation order over (icc,ic,tap) is bitwise identical
// to R5/R8 — rank-sensitive downstream (R6 lesson).
__global__ __launch_bounds__(192) void k_conv(const float* __restrict__ x,
                                              const float* __restrict__ wt,
                                              float* __restrict__ part) {
  __shared__ float xs[16 * 10 * 52];  // 16 ic x 10 rows x 52 cols = 33,280 B
  const int tid = threadIdx.x;
  const int ks = blockIdx.x;
  const int pxc = blockIdx.y;
  const int oc0 = blockIdx.z * 16;
  const int px0 = pxc * 384 + 2 * tid;   // even; this thread: px0, px0+1
  const int col = px0 % 48;              // 0,2,..,46
  const int r0 = pxc * 8;                // first row of this 8-row chunk
  const int rbase = (2 * tid) / 48;      // 0..7

  float accA[16], accB[16];
#pragma unroll
  for (int k = 0; k < 16; ++k) { accA[k] = 0.f; accB[k] = 0.f; }

  for (int icc = 0; icc < 2; ++icc) {
    const int ic0 = ks * 32 + icc * 16;
    // stage x: 16 ic x rows r0-1..r0+8 x cols -1..48 (zero halo)
    for (int e = tid; e < 16 * 10 * 50; e += 192) {
      int ic = e / 500, rem = e % 500;
      int r = rem / 50, c = rem % 50 - 1;
      int gr = r0 - 1 + r;
      float v = 0.f;
      if (c >= 0 && c < 48 && gr >= 0 && gr < 48)
        v = x[(ic0 + ic) * NPX + gr * 48 + c];
      xs[(ic * 10 + r) * 52 + (c + 1)] = v;
    }
    __syncthreads();
    for (int ic = 0; ic < 16; ++ic) {
      float xv[3][4];  // rows rbase-1..+1, cols col-1..col+2
#pragma unroll
      for (int dr = 0; dr < 3; ++dr)
#pragma unroll
        for (int dc = 0; dc < 4; ++dc)
          xv[dr][dc] = xs[(ic * 10 + rbase + dr) * 52 + col + dc];
      const float* wrow = wt + (size_t)(ic0 + ic) * 9 * 256 + oc0;
#pragma unroll
      for (int dr = 0; dr < 3; ++dr)
#pragma unroll
        for (int dc = 0; dc < 3; ++dc) {
          const float* wp = wrow + (dr * 3 + dc) * 256;  // wave-uniform
          float xa = xv[dr][dc], xb = xv[dr][dc + 1];
#pragma unroll
          for (int k = 0; k < 16; ++k) {
            float w = wp[k];
            accA[k] += xa * w;
            accB[k] += xb * w;
          }
        }
    }
    __syncthreads();
  }
#pragma unroll
  for (int k = 0; k < 16; ++k) {
    float2 v = make_float2(accA[k], accB[k]);
    *(float2*)&part[((size_t)ks * 256 + oc0 + k) * NPX + px0] = v;  // coalesced
  }
}

// ---------------- heads + anchor decode (144 blocks x 64 thr) --------------
// Per-pixel summation tree IDENTICAL to R5 (4 c-quarters, 64 sequential
// channels each, left-assoc 4-way reduce) — DO NOT change (R6 lesson).
__global__ __launch_bounds__(64) void k_decode(const float* __restrict__ part,
                                               const float* __restrict__ cb,
                                               const float* __restrict__ dw,
                                               const float* __restrict__ db,
                                               const float* __restrict__ rw,
                                               const float* __restrict__ rb,
                                               const float* __restrict__ anch,
                                               float* __restrict__ s,
                                               float4* __restrict__ boxes) {
  __shared__ float wl[256 * 16];        // 16 KB  [c][o]
  __shared__ float red[64 * 17];        // [cq*16+pxl][o], stride 17
  const int tid = threadIdx.x;
  const int pxl = tid & 15;
  const int cq = tid >> 4;              // 0..3
  const int px = blockIdx.x * 16 + pxl;
  for (int e = tid; e < 3840; e += 64) {
    int o = e % 15, c = e / 15;
    wl[c * 16 + o] = (o < 3) ? dw[o * 256 + c] : rw[(o - 3) * 256 + c];
  }
  __syncthreads();
  float acc[15];
#pragma unroll
  for (int o = 0; o < 15; o++) acc[o] = 0.f;
  for (int ci = 0; ci < 64; ++ci) {
    int c = cq * 64 + ci;
    float v = cb[c];
#pragma unroll
    for (int kks = 0; kks < KSPLIT; ++kks)
      v += part[((size_t)kks * 256 + c) * NPX + px];
#pragma unroll
    for (int o = 0; o < 15; o++) acc[o] += v * wl[c * 16 + o];
  }
#pragma unroll
  for (int o = 0; o < 15; o++) red[(cq * 16 + pxl) * 17 + o] = acc[o];
  __syncthreads();
  if (tid < 48) {
    int aa = tid / 16, p2 = tid % 16;
    int p = blockIdx.x * 16 + p2;
    int m = aa * NPX + p;
#define RSUM(o) (red[p2 * 17 + (o)] + red[(16 + p2) * 17 + (o)] + \
                 red[(32 + p2) * 17 + (o)] + red[(48 + p2) * 17 + (o)])
    float logit = RSUM(aa) + db[aa];
    float score = 1.f / (1.f + expf(-logit));
    float dxv = RSUM(3 + aa) + rb[0 + aa];
    float dyv = RSUM(6 + aa) + rb[3 + aa];
    float dwv = RSUM(9 + aa) + rb[6 + aa];
    float dhv = RSUM(12 + aa) + rb[9 + aa];
#undef RSUM
    float4 an = ((const float4*)anch)[m];
    float aw = an.z - an.x;
    float ah = an.w - an.y;
    float acx = an.y + aw * 0.5f;  // NOTE: intentionally swapped (reference quirk)
    float acy = an.x + ah * 0.5f;  // NOTE: intentionally swapped (reference quirk)
    float pxc = acx + dxv * aw;
    float pyc = acy + dyv * ah;
    float pw = aw * expf(dwv);
    float ph = ah * expf(dhv);
    float b0 = pxc - pw * 0.5f, b1 = pyc - ph * 0.5f;
    float b2 = pxc + pw * 0.5f, b3 = pyc + ph * 0.5f;
    b0 = fminf(fmaxf(b0, 0.f), IMGF);
    b1 = fminf(fmaxf(b1, 0.f), IMGF);
    b2 = fminf(fmaxf(b2, 0.f), IMGF);
    b3 = fminf(fmaxf(b3, 0.f), IMGF);
    float hts = b2 - b0, wds = b3 - b1;
    bool valid = (hts > 0.f) && (wds > 0.f) && (score > OBJ_THRF);
    s[m] = valid ? score : NEGV;
    boxes[m] = make_float4(b0, b1, b2, b3);
  }
}

// ---------------- sort phase 1: bitonic runs + nz zero-init ----------------
// nz zeroing lives here: part (which overlaps nz) is dead after k_decode.
__global__ __launch_bounds__(256) void k_sortA(const float* __restrict__ s,
                                               u64* __restrict__ keys,
                                               u64* __restrict__ nz) {
  __shared__ u64 lds[1024];
  const int tid = threadIdx.x;
  const int b = blockIdx.x;
  for (int i = b * 256 + tid; i < MM * 2; i += 8 * 256) nz[i] = 0;
  for (int v = tid; v < 1024; v += 256) {
    int i = b * 1024 + v;
    u64 p;
    if (i < MM) {
      u32 u = __float_as_uint(s[i]);
      u = u ^ (u32)(((int)u >> 31) | 0x80000000);
      p = ((u64)(~u) << 32) | (u32)i;
    } else {
      p = ~0ull;
    }
    lds[v] = p;
  }
  for (u32 kk = 2; kk <= 1024; kk <<= 1) {
    for (u32 j = kk >> 1; j > 0; j >>= 1) {
      __syncthreads();
#pragma unroll 2
      for (int t = tid; t < 512; t += 256) {
        int i = ((t & ~(j - 1)) << 1) | (t & (j - 1));
        int l = i | j;
        bool up = ((i & kk) == 0);
        u64 a = lds[i], c = lds[l];
        u64 mn = a < c ? a : c;
        u64 mx = a < c ? c : a;
        lds[i] = up ? mn : mx;
        lds[l] = up ? mx : mn;
      }
    }
  }
  __syncthreads();
  for (int v = tid; v < 1024; v += 256) keys[b * 1024 + v] = lds[v];
}

// ---------------- sort phase 2: merge-path rounds ----------------
__global__ __launch_bounds__(256) void k_merge(const u64* __restrict__ in,
                                               u64* __restrict__ outk, int L, int fin,
                                               const float* __restrict__ s,
                                               const float4* __restrict__ boxes,
                                               float* __restrict__ ssc,
                                               float4* __restrict__ sboxes) {
  const int i = blockIdx.x * 256 + threadIdx.x;  // 0..8191
  const int pair = i / (2 * L);
  const int r = i - pair * 2 * L;
  const u64* A = in + (size_t)pair * 2 * L;
  const u64* B = A + L;
  int lo = (r > L) ? (r - L) : 0;
  int hi = (r < L) ? r : L;
  while (lo < hi) {
    int mid = (lo + hi) >> 1;
    if (A[mid] < B[r - 1 - mid]) lo = mid + 1; else hi = mid;
  }
  int a = lo, bi = r - lo;
  u64 av = (a < L) ? A[a] : ~0ull;
  u64 bv = (bi < L) ? B[bi] : ~0ull;
  u64 o = (av < bv) ? av : bv;
  outk[i] = o;
  if (fin && i < MM) {
    int idx = (int)(u32)o;
    ssc[i] = s[idx];
    sboxes[i] = boxes[idx];
  }
}

// ---------------- IOU suppression bit-matrix (transposed) ----------------
__global__ __launch_bounds__(256) void k_mask(const float4* __restrict__ sboxes,
                                              u64* __restrict__ mask_t,
                                              u64* __restrict__ nz) {
  __shared__ float4 rb_[64];
  const int rt = blockIdx.x;
  const int w = blockIdx.y * 4 + (threadIdx.x >> 6);
  const int lane = threadIdx.x & 63;
  if (threadIdx.x < 64) rb_[threadIdx.x] = sboxes[rt * 64 + threadIdx.x];
  __syncthreads();
  if (w < rt) return;
  float4 c = sboxes[w * 64 + lane];
  float areaC = (c.z - c.x) * (c.w - c.y);
  u64 myw = 0;
  for (int r = 0; r < 64; ++r) {
    float4 b = rb_[r];
    float iw = fmaxf(fminf(b.z, c.z) - fmaxf(b.x, c.x), 0.f);
    float ih = fmaxf(fminf(b.w, c.w) - fmaxf(b.y, c.y), 0.f);
    float inter = iw * ih;
    float areaB = (b.z - b.x) * (b.w - b.y);
    float un = fmaxf(areaB + areaC - inter, 1e-9f);
    bool bit = (inter / un) > IOU_THRF;
    u64 bal = __ballot(bit);
    if (lane == r) myw = bal;
  }
  mask_t[(size_t)w * MM + rt * 64 + lane] = myw;
  if (myw) atomicOr(&nz[(rt * 64 + lane) * 2 + (w >> 6)], 1ull << (w & 63));
}

// ---------------- NMS scan: single wave, zero barriers, prefetched --------
__global__ __launch_bounds__(64) void k_scan(const u64* __restrict__ mask_t,
                                             const u64* __restrict__ nz,
                                             const float* __restrict__ ssc,
                                             const float4* __restrict__ sboxes,
                                             float* __restrict__ out) {
  __shared__ u64 remv[NW];
  __shared__ u64 keepw[NW];
  __shared__ int pref[NW];
  const int lane = threadIdx.x;
  for (int i = lane; i < NW; i += 64) { remv[i] = 0; keepw[i] = 0; }
  int kcnt = 0;
  u64 dg = mask_t[lane];            // chunk 0 diagonal word (c=0)
  float sv = ssc[lane];
  for (int c = 0; c < NW; ++c) {
    u64 dg_n = 0; float sv_n = 0.f;
    if (c + 1 < NW) {               // prefetch next chunk (read-only, safe)
      dg_n = mask_t[(size_t)(c + 1) * MM + (c + 1) * 64 + lane];
      sv_n = ssc[(c + 1) * 64 + lane];
    }
    u64 vb = __ballot(sv > OBJ_THRF);
    u64 w0 = remv[c];
    u64 cand = vb & ~w0;
    u64 above = (lane < 63) ? ~((2ull << lane) - 1ull) : 0ull;
    bool inC = ((cand >> lane) & 1ull) != 0;
    u64 conf = __ballot(inC && ((dg & above & cand) != 0ull));
    u64 kb;
    if (conf == 0ull) {
      kb = cand;  // fast path: no intra-chunk suppression among candidates
    } else {
      u64 w = w0; kb = 0;
      u64 rem = cand;
      while (rem) {
        int b = __ffsll(rem) - 1;
        kb |= (1ull << b);
        w |= shfl64(dg, b);
        rem = vb & ~w;
      }
    }
    if (lane == 0) keepw[c] = kb;
    // lane-parallel sparse propagation: each kept row handled by its own lane
    if ((kb >> lane) & 1ull) {
      int rowi = c * 64 + lane;
      u64 nz0 = nz[rowi * 2], nz1 = nz[rowi * 2 + 1];
      if (c < 64) {
        nz0 &= (c < 63) ? ~((2ull << c) - 1ull) : 0ull;
      } else {
        nz0 = 0;
        nz1 &= ~((2ull << (c - 64)) - 1ull);
      }
      while (nz0) {
        int wv = __ffsll(nz0) - 1; nz0 &= nz0 - 1;
        atomicOr(&remv[wv], mask_t[(size_t)wv * MM + rowi]);
      }
      while (nz1) {
        int wv = __ffsll(nz1) - 1; nz1 &= nz1 - 1;
        atomicOr(&remv[wv + 64], mask_t[(size_t)(wv + 64) * MM + rowi]);
      }
    }
    kcnt += __popcll(kb);
    dg = dg_n; sv = sv_n;
    if (kcnt >= TOPK) break;  // only top-2000 kept are ever output
  }

  if (lane == 0) {
    int run = 0;
    for (int cc = 0; cc < NW; ++cc) { pref[cc] = run; run += __popcll(keepw[cc]); }
  }
  for (int e = lane; e < TOPK * 5; e += 64) out[e] = (e < TOPK) ? -1.0f : 0.0f;
  float4* ob = (float4*)(out + TOPK);
  for (int i = lane; i < MM; i += 64) {
    int cc = i >> 6, b = i & 63;
    u64 kb = keepw[cc];
    if ((kb >> b) & 1ull) {
      int rank = pref[cc] + __popcll(kb & ((1ull << b) - 1ull));
      if (rank < TOPK) {
        out[rank] = ssc[i];
        ob[rank] = sboxes[i];
      }
    }
  }
}

extern "C" void kernel_launch(void* const* d_in, const int* in_sizes, int n_in,
                              void* d_out, int out_size, void* d_ws, size_t ws_size,
                              hipStream_t stream) {
  const float* x  = (const float*)d_in[0];
  const float* cw = (const float*)d_in[1];
  const float* cb = (const float*)d_in[2];
  const float* dw = (const float*)d_in[3];
  const float* db = (const float*)d_in[4];
  const float* rw = (const float*)d_in[5];
  const float* rb = (const float*)d_in[6];
  const float* an = (const float*)d_in[7];
  char* ws = (char*)d_ws;
  // Time-phased aliasing of [0 .. 18.9MB):
  //   phase 1 (k_wt,k_conv,k_decode): part
  //   phase 2 (k_sortA..k_merge): keysA/B at [0..128KB), nz at 5,971,968
  //     (nz zeroed in k_sortA — part dead there; zeroing earlier would be
  //      overwritten by part, R6 lesson)
  //   phase 3 (k_mask,k_scan): mask at [0..5,971,968)
  float*  part   = (float*)(ws);                 // 18,874,368 B (KSPLIT*256*NPX*4)
  u64*    keysA  = (u64*)(ws);                   // 65,536 B
  u64*    keysB  = (u64*)(ws + 65536);           // 65,536 B
  u64*    mask   = (u64*)(ws);                   // 5,971,968 B
  u64*    nz     = (u64*)(ws + 5971968);         // 110,592 B
  float*  wt     = (float*)(ws + 18874368);      // 2,359,296 B
  float*  s      = (float*)(ws + 21233664);      // 27,648 B
  float4* boxes  = (float4*)(ws + 21261312);     // 110,592 B
  float*  ssc    = (float*)(ws + 21371904);      // 27,648 B
  float4* sboxes = (float4*)(ws + 21399552);     // 110,592 B -> total 21,510,144 B
  float* out = (float*)d_out;

  hipLaunchKernelGGL(k_wt, dim3(36, 4), dim3(256), 0, stream, cw, wt);
  hipLaunchKernelGGL(k_conv, dim3(KSPLIT, 6, 16), dim3(192), 0, stream, x, wt, part);
  hipLaunchKernelGGL(k_decode, dim3(144), dim3(64), 0, stream, part, cb, dw, db, rw, rb, an, s, boxes);
  hipLaunchKernelGGL(k_sortA, dim3(8), dim3(256), 0, stream, s, keysA, nz);
  hipLaunchKernelGGL(k_merge, dim3(32), dim3(256), 0, stream, keysA, keysB, 1024, 0, s, boxes, ssc, sboxes);
  hipLaunchKernelGGL(k_merge, dim3(32), dim3(256), 0, stream, keysB, keysA, 2048, 0, s, boxes, ssc, sboxes);
  hipLaunchKernelGGL(k_merge, dim3(32), dim3(256), 0, stream, keysA, keysB, 4096, 1, s, boxes, ssc, sboxes);
  hipLaunchKernelGGL(k_mask, dim3(108, 27), dim3(256), 0, stream, sboxes, mask, nz);
  hipLaunchKernelGGL(k_scan, dim3(1), dim3(64), 0, stream, mask, nz, ssc, sboxes, out);
}

// Round 10
// 267.540 us; speedup vs baseline: 1.0357x; 1.0357x over previous
//
#include <hip/hip_runtime.h>
#include <cstdint>

#define NPX 2304      // 48*48
#define MM 6912       // 3*2304
#define NW 108        // MM/64
#define TOPK 2000
#define NEGV -1000000000.0f
#define OBJ_THRF 0.3f
#define IOU_THRF 0.7f
#define IMGF 768.0f
#define KSPLIT 8      // conv k-splits: 32 ic per split

typedef unsigned long long u64;
typedef unsigned int u32;

__device__ __forceinline__ u64 shfl64(u64 v, int src) {
  int lo = __shfl((int)(v & 0xffffffffull), src, 64);
  int hi = __shfl((int)(v >> 32), src, 64);
  return ((u64)(u32)hi << 32) | (u32)lo;
}

// ---------------- weight transpose ----------------
__global__ __launch_bounds__(256) void k_wt(const float* __restrict__ cw,
                                            float* __restrict__ wt) {
  __shared__ float t[64][65];
  const int it0 = blockIdx.x * 64;   // grid.x = 36 (2304/64)
  const int oc0 = blockIdx.y * 64;   // grid.y = 4
  const int tx = threadIdx.x & 63;
  const int ty = threadIdx.x >> 6;
#pragma unroll
  for (int k = 0; k < 16; ++k) {
    int oc = ty + k * 4;
    t[oc][tx] = cw[(oc0 + oc) * 2304 + it0 + tx];  // coalesced read
  }
  __syncthreads();
#pragma unroll
  for (int k = 0; k < 16; ++k) {
    int it = ty + k * 4;
    wt[(it0 + it) * 256 + oc0 + tx] = t[tx][it];   // coalesced write
  }
}

// ---------------- conv 3x3, 256->256, fp32, scalar-weight form ----------------
// grid (8 ks, 6 px-chunks, 32 oc-tiles) = 1536 blocks x 192 thr (3 waves).
// XCD property: same-ks blocks share blockid%8 -> same XCD; x+wt L2-resident
// (R7: FETCH 27.7 -> 3.5 MB).
// Design (R7/R8/R9 evidence):
//  - 8 oc/thread: weight stream/block = 8KB+ fits 16KB scalar K$ (R8's 16-oc
//    18KB thrashed it -> s_load L2 misses -> 51% VALUBusy plateau).
//  - 2 px VERTICAL pair/thread: 144 FMA/ic under a 72-float weight window,
//    12 LDS xv reads/ic (6/px), natural col order (R9's even-col pattern
//    doubled conflicts), coalesced 48-lane stores.
//  - ic-tile 8: LDS 16.6KB -> 6 resident blocks/CU = 18 waves/CU.
// NOTE: per-(px,oc) accumulation order over (global ic, tap) is bitwise
// identical to R5/R8 — rank-sensitive downstream (R6 lesson).
__global__ __launch_bounds__(192) void k_conv(const float* __restrict__ x,
                                              const float* __restrict__ wt,
                                              float* __restrict__ part) {
  __shared__ float xs[8 * 10 * 52];  // 8 ic x 10 rows x 52 cols = 16,640 B
  const int tid = threadIdx.x;
  const int ks = blockIdx.x;
  const int pxc = blockIdx.y;
  const int oc0 = blockIdx.z * 8;
  const int rp = tid / 48;           // row-pair 0..3
  const int col = tid % 48;
  const int r0 = pxc * 8;            // first row of this 8-row chunk
  const int row0 = r0 + 2 * rp;      // this thread: rows row0, row0+1
  const int px0 = row0 * 48 + col;

  float accA[8], accB[8];
#pragma unroll
  for (int k = 0; k < 8; ++k) { accA[k] = 0.f; accB[k] = 0.f; }

  for (int icc = 0; icc < 4; ++icc) {
    const int ic0 = ks * 32 + icc * 8;
    // stage x: 8 ic x rows r0-1..r0+8 x cols -1..48 (zero halo)
    for (int e = tid; e < 8 * 10 * 50; e += 192) {
      int ic = e / 500, rem = e % 500;
      int r = rem / 50, c = rem % 50 - 1;
      int gr = r0 - 1 + r;
      float v = 0.f;
      if (c >= 0 && c < 48 && gr >= 0 && gr < 48)
        v = x[(ic0 + ic) * NPX + gr * 48 + c];
      xs[(ic * 10 + r) * 52 + (c + 1)] = v;
    }
    __syncthreads();
    for (int ic = 0; ic < 8; ++ic) {
      float xv[4][3];  // stage rows 2rp..2rp+3, cols col-1..col+1
#pragma unroll
      for (int dr = 0; dr < 4; ++dr)
#pragma unroll
        for (int dc = 0; dc < 3; ++dc)
          xv[dr][dc] = xs[(ic * 10 + 2 * rp + dr) * 52 + col + dc];
      const float* wrow = wt + (size_t)(ic0 + ic) * 9 * 256 + oc0;
#pragma unroll
      for (int dr = 0; dr < 3; ++dr)
#pragma unroll
        for (int dc = 0; dc < 3; ++dc) {
          const float* wp = wrow + (dr * 3 + dc) * 256;  // wave-uniform
          float xa = xv[dr][dc];       // row0's tap
          float xb = xv[dr + 1][dc];   // row0+1's tap
#pragma unroll
          for (int k = 0; k < 8; ++k) {
            float w = wp[k];
            accA[k] += xa * w;
            accB[k] += xb * w;
          }
        }
    }
    __syncthreads();
  }
#pragma unroll
  for (int k = 0; k < 8; ++k) {
    part[((size_t)ks * 256 + oc0 + k) * NPX + px0] = accA[k];        // coalesced
    part[((size_t)ks * 256 + oc0 + k) * NPX + px0 + 48] = accB[k];   // coalesced
  }
}

// ---------------- heads + anchor decode (144 blocks x 64 thr) --------------
// Per-pixel summation tree IDENTICAL to R5 (4 c-quarters, 64 sequential
// channels each, left-assoc 4-way reduce) — DO NOT change (R6 lesson).
__global__ __launch_bounds__(64) void k_decode(const float* __restrict__ part,
                                               const float* __restrict__ cb,
                                               const float* __restrict__ dw,
                                               const float* __restrict__ db,
                                               const float* __restrict__ rw,
                                               const float* __restrict__ rb,
                                               const float* __restrict__ anch,
                                               float* __restrict__ s,
                                               float4* __restrict__ boxes) {
  __shared__ float wl[256 * 16];        // 16 KB  [c][o]
  __shared__ float red[64 * 17];        // [cq*16+pxl][o], stride 17
  const int tid = threadIdx.x;
  const int pxl = tid & 15;
  const int cq = tid >> 4;              // 0..3
  const int px = blockIdx.x * 16 + pxl;
  for (int e = tid; e < 3840; e += 64) {
    int o = e % 15, c = e / 15;
    wl[c * 16 + o] = (o < 3) ? dw[o * 256 + c] : rw[(o - 3) * 256 + c];
  }
  __syncthreads();
  float acc[15];
#pragma unroll
  for (int o = 0; o < 15; o++) acc[o] = 0.f;
  for (int ci = 0; ci < 64; ++ci) {
    int c = cq * 64 + ci;
    float v = cb[c];
#pragma unroll
    for (int kks = 0; kks < KSPLIT; ++kks)
      v += part[((size_t)kks * 256 + c) * NPX + px];
#pragma unroll
    for (int o = 0; o < 15; o++) acc[o] += v * wl[c * 16 + o];
  }
#pragma unroll
  for (int o = 0; o < 15; o++) red[(cq * 16 + pxl) * 17 + o] = acc[o];
  __syncthreads();
  if (tid < 48) {
    int aa = tid / 16, p2 = tid % 16;
    int p = blockIdx.x * 16 + p2;
    int m = aa * NPX + p;
#define RSUM(o) (red[p2 * 17 + (o)] + red[(16 + p2) * 17 + (o)] + \
                 red[(32 + p2) * 17 + (o)] + red[(48 + p2) * 17 + (o)])
    float logit = RSUM(aa) + db[aa];
    float score = 1.f / (1.f + expf(-logit));
    float dxv = RSUM(3 + aa) + rb[0 + aa];
    float dyv = RSUM(6 + aa) + rb[3 + aa];
    float dwv = RSUM(9 + aa) + rb[6 + aa];
    float dhv = RSUM(12 + aa) + rb[9 + aa];
#undef RSUM
    float4 an = ((const float4*)anch)[m];
    float aw = an.z - an.x;
    float ah = an.w - an.y;
    float acx = an.y + aw * 0.5f;  // NOTE: intentionally swapped (reference quirk)
    float acy = an.x + ah * 0.5f;  // NOTE: intentionally swapped (reference quirk)
    float pxc = acx + dxv * aw;
    float pyc = acy + dyv * ah;
    float pw = aw * expf(dwv);
    float ph = ah * expf(dhv);
    float b0 = pxc - pw * 0.5f, b1 = pyc - ph * 0.5f;
    float b2 = pxc + pw * 0.5f, b3 = pyc + ph * 0.5f;
    b0 = fminf(fmaxf(b0, 0.f), IMGF);
    b1 = fminf(fmaxf(b1, 0.f), IMGF);
    b2 = fminf(fmaxf(b2, 0.f), IMGF);
    b3 = fminf(fmaxf(b3, 0.f), IMGF);
    float hts = b2 - b0, wds = b3 - b1;
    bool valid = (hts > 0.f) && (wds > 0.f) && (score > OBJ_THRF);
    s[m] = valid ? score : NEGV;
    boxes[m] = make_float4(b0, b1, b2, b3);
  }
}

// ---------------- sort phase 1: bitonic runs + nz zero-init ----------------
// nz zeroing lives here: part (which overlaps nz) is dead after k_decode.
__global__ __launch_bounds__(256) void k_sortA(const float* __restrict__ s,
                                               u64* __restrict__ keys,
                                               u64* __restrict__ nz) {
  __shared__ u64 lds[1024];
  const int tid = threadIdx.x;
  const int b = blockIdx.x;
  for (int i = b * 256 + tid; i < MM * 2; i += 8 * 256) nz[i] = 0;
  for (int v = tid; v < 1024; v += 256) {
    int i = b * 1024 + v;
    u64 p;
    if (i < MM) {
      u32 u = __float_as_uint(s[i]);
      u = u ^ (u32)(((int)u >> 31) | 0x80000000);
      p = ((u64)(~u) << 32) | (u32)i;
    } else {
      p = ~0ull;
    }
    lds[v] = p;
  }
  for (u32 kk = 2; kk <= 1024; kk <<= 1) {
    for (u32 j = kk >> 1; j > 0; j >>= 1) {
      __syncthreads();
#pragma unroll 2
      for (int t = tid; t < 512; t += 256) {
        int i = ((t & ~(j - 1)) << 1) | (t & (j - 1));
        int l = i | j;
        bool up = ((i & kk) == 0);
        u64 a = lds[i], c = lds[l];
        u64 mn = a < c ? a : c;
        u64 mx = a < c ? c : a;
        lds[i] = up ? mn : mx;
        lds[l] = up ? mx : mn;
      }
    }
  }
  __syncthreads();
  for (int v = tid; v < 1024; v += 256) keys[b * 1024 + v] = lds[v];
}

// ---------------- sort phase 2: merge-path rounds ----------------
__global__ __launch_bounds__(256) void k_merge(const u64* __restrict__ in,
                                               u64* __restrict__ outk, int L, int fin,
                                               const float* __restrict__ s,
                                               const float4* __restrict__ boxes,
                                               float* __restrict__ ssc,
                                               float4* __restrict__ sboxes) {
  const int i = blockIdx.x * 256 + threadIdx.x;  // 0..8191
  const int pair = i / (2 * L);
  const int r = i - pair * 2 * L;
  const u64* A = in + (size_t)pair * 2 * L;
  const u64* B = A + L;
  int lo = (r > L) ? (r - L) : 0;
  int hi = (r < L) ? r : L;
  while (lo < hi) {
    int mid = (lo + hi) >> 1;
    if (A[mid] < B[r - 1 - mid]) lo = mid + 1; else hi = mid;
  }
  int a = lo, bi = r - lo;
  u64 av = (a < L) ? A[a] : ~0ull;
  u64 bv = (bi < L) ? B[bi] : ~0ull;
  u64 o = (av < bv) ? av : bv;
  outk[i] = o;
  if (fin && i < MM) {
    int idx = (int)(u32)o;
    ssc[i] = s[idx];
    sboxes[i] = boxes[idx];
  }
}

// ---------------- IOU suppression bit-matrix (transposed) ----------------
__global__ __launch_bounds__(256) void k_mask(const float4* __restrict__ sboxes,
                                              u64* __restrict__ mask_t,
                                              u64* __restrict__ nz) {
  __shared__ float4 rb_[64];
  const int rt = blockIdx.x;
  const int w = blockIdx.y * 4 + (threadIdx.x >> 6);
  const int lane = threadIdx.x & 63;
  if (threadIdx.x < 64) rb_[threadIdx.x] = sboxes[rt * 64 + threadIdx.x];
  __syncthreads();
  if (w < rt) return;
  float4 c = sboxes[w * 64 + lane];
  float areaC = (c.z - c.x) * (c.w - c.y);
  u64 myw = 0;
  for (int r = 0; r < 64; ++r) {
    float4 b = rb_[r];
    float iw = fmaxf(fminf(b.z, c.z) - fmaxf(b.x, c.x), 0.f);
    float ih = fmaxf(fminf(b.w, c.w) - fmaxf(b.y, c.y), 0.f);
    float inter = iw * ih;
    float areaB = (b.z - b.x) * (b.w - b.y);
    float un = fmaxf(areaB + areaC - inter, 1e-9f);
    bool bit = (inter / un) > IOU_THRF;
    u64 bal = __ballot(bit);
    if (lane == r) myw = bal;
  }
  mask_t[(size_t)w * MM + rt * 64 + lane] = myw;
  if (myw) atomicOr(&nz[(rt * 64 + lane) * 2 + (w >> 6)], 1ull << (w & 63));
}

// ---------------- NMS scan: single wave, zero barriers, prefetched --------
__global__ __launch_bounds__(64) void k_scan(const u64* __restrict__ mask_t,
                                             const u64* __restrict__ nz,
                                             const float* __restrict__ ssc,
                                             const float4* __restrict__ sboxes,
                                             float* __restrict__ out) {
  __shared__ u64 remv[NW];
  __shared__ u64 keepw[NW];
  __shared__ int pref[NW];
  const int lane = threadIdx.x;
  for (int i = lane; i < NW; i += 64) { remv[i] = 0; keepw[i] = 0; }
  int kcnt = 0;
  u64 dg = mask_t[lane];            // chunk 0 diagonal word (c=0)
  float sv = ssc[lane];
  for (int c = 0; c < NW; ++c) {
    u64 dg_n = 0; float sv_n = 0.f;
    if (c + 1 < NW) {               // prefetch next chunk (read-only, safe)
      dg_n = mask_t[(size_t)(c + 1) * MM + (c + 1) * 64 + lane];
      sv_n = ssc[(c + 1) * 64 + lane];
    }
    u64 vb = __ballot(sv > OBJ_THRF);
    u64 w0 = remv[c];
    u64 cand = vb & ~w0;
    u64 above = (lane < 63) ? ~((2ull << lane) - 1ull) : 0ull;
    bool inC = ((cand >> lane) & 1ull) != 0;
    u64 conf = __ballot(inC && ((dg & above & cand) != 0ull));
    u64 kb;
    if (conf == 0ull) {
      kb = cand;  // fast path: no intra-chunk suppression among candidates
    } else {
      u64 w = w0; kb = 0;
      u64 rem = cand;
      while (rem) {
        int b = __ffsll(rem) - 1;
        kb |= (1ull << b);
        w |= shfl64(dg, b);
        rem = vb & ~w;
      }
    }
    if (lane == 0) keepw[c] = kb;
    // lane-parallel sparse propagation: each kept row handled by its own lane
    if ((kb >> lane) & 1ull) {
      int rowi = c * 64 + lane;
      u64 nz0 = nz[rowi * 2], nz1 = nz[rowi * 2 + 1];
      if (c < 64) {
        nz0 &= (c < 63) ? ~((2ull << c) - 1ull) : 0ull;
      } else {
        nz0 = 0;
        nz1 &= ~((2ull << (c - 64)) - 1ull);
      }
      while (nz0) {
        int wv = __ffsll(nz0) - 1; nz0 &= nz0 - 1;
        atomicOr(&remv[wv], mask_t[(size_t)wv * MM + rowi]);
      }
      while (nz1) {
        int wv = __ffsll(nz1) - 1; nz1 &= nz1 - 1;
        atomicOr(&remv[wv + 64], mask_t[(size_t)(wv + 64) * MM + rowi]);
      }
    }
    kcnt += __popcll(kb);
    dg = dg_n; sv = sv_n;
    if (kcnt >= TOPK) break;  // only top-2000 kept are ever output
  }

  if (lane == 0) {
    int run = 0;
    for (int cc = 0; cc < NW; ++cc) { pref[cc] = run; run += __popcll(keepw[cc]); }
  }
  for (int e = lane; e < TOPK * 5; e += 64) out[e] = (e < TOPK) ? -1.0f : 0.0f;
  float4* ob = (float4*)(out + TOPK);
  for (int i = lane; i < MM; i += 64) {
    int cc = i >> 6, b = i & 63;
    u64 kb = keepw[cc];
    if ((kb >> b) & 1ull) {
      int rank = pref[cc] + __popcll(kb & ((1ull << b) - 1ull));
      if (rank < TOPK) {
        out[rank] = ssc[i];
        ob[rank] = sboxes[i];
      }
    }
  }
}

extern "C" void kernel_launch(void* const* d_in, const int* in_sizes, int n_in,
                              void* d_out, int out_size, void* d_ws, size_t ws_size,
                              hipStream_t stream) {
  const float* x  = (const float*)d_in[0];
  const float* cw = (const float*)d_in[1];
  const float* cb = (const float*)d_in[2];
  const float* dw = (const float*)d_in[3];
  const float* db = (const float*)d_in[4];
  const float* rw = (const float*)d_in[5];
  const float* rb = (const float*)d_in[6];
  const float* an = (const float*)d_in[7];
  char* ws = (char*)d_ws;
  // Time-phased aliasing of [0 .. 18.9MB):
  //   phase 1 (k_wt,k_conv,k_decode): part
  //   phase 2 (k_sortA..k_merge): keysA/B at [0..128KB), nz at 5,971,968
  //     (nz zeroed in k_sortA — part dead there; zeroing earlier would be
  //      overwritten by part, R6 lesson)
  //   phase 3 (k_mask,k_scan): mask at [0..5,971,968)
  float*  part   = (float*)(ws);                 // 18,874,368 B (KSPLIT*256*NPX*4)
  u64*    keysA  = (u64*)(ws);                   // 65,536 B
  u64*    keysB  = (u64*)(ws + 65536);           // 65,536 B
  u64*    mask   = (u64*)(ws);                   // 5,971,968 B
  u64*    nz     = (u64*)(ws + 5971968);         // 110,592 B
  float*  wt     = (float*)(ws + 18874368);      // 2,359,296 B
  float*  s      = (float*)(ws + 21233664);      // 27,648 B
  float4* boxes  = (float4*)(ws + 21261312);     // 110,592 B
  float*  ssc    = (float*)(ws + 21371904);      // 27,648 B
  float4* sboxes = (float4*)(ws + 21399552);     // 110,592 B -> total 21,510,144 B
  float* out = (float*)d_out;

  hipLaunchKernelGGL(k_wt, dim3(36, 4), dim3(256), 0, stream, cw, wt);
  hipLaunchKernelGGL(k_conv, dim3(KSPLIT, 6, 32), dim3(192), 0, stream, x, wt, part);
  hipLaunchKernelGGL(k_decode, dim3(144), dim3(64), 0, stream, part, cb, dw, db, rw, rb, an, s, boxes);
  hipLaunchKernelGGL(k_sortA, dim3(8), dim3(256), 0, stream, s, keysA, nz);
  hipLaunchKernelGGL(k_merge, dim3(32), dim3(256), 0, stream, keysA, keysB, 1024, 0, s, boxes, ssc, sboxes);
  hipLaunchKernelGGL(k_merge, dim3(32), dim3(256), 0, stream, keysB, keysA, 2048, 0, s, boxes, ssc, sboxes);
  hipLaunchKernelGGL(k_merge, dim3(32), dim3(256), 0, stream, keysA, keysB, 4096, 1, s, boxes, ssc, sboxes);
  hipLaunchKernelGGL(k_mask, dim3(108, 27), dim3(256), 0, stream, sboxes, mask, nz);
  hipLaunchKernelGGL(k_scan, dim3(1), dim3(64), 0, stream, mask, nz, ssc, sboxes, out);
}